// Round 13
// baseline (203.923 us; speedup 1.0000x reference)
//
#include <hip/hip_runtime.h>
#include <math.h>

#define B 2
#define N 8192
#define M 8192
#define D 64
#define KNN 16
#define BM (B * M)           // 16384
#define GC 16                // grid cells per axis
#define NC (GC * GC * GC)    // 4096
#define NSC 64               // supercells (4x4x4)
#define WTMAX 192            // max wave-table entries per batch (proven bound)

using frag_ab = __attribute__((ext_vector_type(8))) short;   // 8 bf16 (4 VGPRs)
using frag_cd = __attribute__((ext_vector_type(4))) float;   // 4 fp32

// fp32 -> bf16 (round-to-nearest-even), bits in a short.
__device__ __forceinline__ short f2bf(float x) {
    unsigned u = __float_as_uint(x);
    u += 0x7fffu + ((u >> 16) & 1u);
    return (short)(u >> 16);
}

// Per-query filter radius: lambda~60 expected in-(clipped-)ball candidates.
// nc = #axes within 0.16 of a domain wall (density octant compensation).
// MUST be recomputed identically in k_knn and k_merge.
__device__ __forceinline__ float query_cutr(float qx, float qy, float qz) {
    int nc = ((qx < 0.16f) | (qx > 0.84f)) + ((qy < 0.16f) | (qy > 0.84f))
           + ((qz < 0.16f) | (qz > 0.84f));
    return nc == 0 ? 0.121f : nc == 1 ? 0.1525f : nc == 2 ? 0.1921f : 0.242f;
}

// Sorted-insert of (dd,ii) into a per-lane top-16 (ascending). Strict < keeps
// earlier-inserted on exact ties.
#define CHAIN_INS(VARR, IARR, DVAL, IVAL) do {                          \
    float _dd = (DVAL); int _ii = (IVAL);                               \
    _Pragma("unroll")                                                   \
    for (int _r = 0; _r < KNN; ++_r) {                                  \
        bool  _sm = _dd < VARR[_r];                                     \
        float _tv = VARR[_r]; int _ti = IARR[_r];                       \
        VARR[_r] = _sm ? _dd : _tv;  IARR[_r] = _sm ? _ii : _ti;        \
        _dd      = _sm ? _tv : _dd;  _ii      = _sm ? _ti : _ii;        \
    }                                                                   \
} while (0)
#define CHAIN_INSERT(DVAL, IVAL) CHAIN_INS(v, id, DVAL, IVAL)

// One bitonic-merge round between lane and lane^DL: both keep the lowest 16
// of their combined (sorted) lists, result sorted. VARR/IARR must be sorted
// ascending on entry.
#define BITONIC_ROUND(VARR, IARR, DL) do {                              \
    float _nv[KNN]; int _nid[KNN];                                      \
    _Pragma("unroll")                                                   \
    for (int _i = 0; _i < KNN; ++_i) {                                  \
        float _pv = __shfl_xor(VARR[KNN - 1 - _i], (DL), 64);           \
        int   _pi = __shfl_xor(IARR[KNN - 1 - _i], (DL), 64);           \
        bool _tk = VARR[_i] <= _pv;                                     \
        _nv[_i]  = _tk ? VARR[_i] : _pv;                                \
        _nid[_i] = _tk ? IARR[_i] : _pi;                                \
    }                                                                   \
    _Pragma("unroll")                                                   \
    for (int _st = 8; _st; _st >>= 1) {                                 \
        _Pragma("unroll")                                               \
        for (int _i = 0; _i < KNN; ++_i) {                              \
            if (!(_i & _st)) {                                          \
                int _j = _i | _st;                                      \
                bool _sw = _nv[_i] > _nv[_j];                           \
                float _ta = _sw ? _nv[_j] : _nv[_i];                    \
                float _tb = _sw ? _nv[_i] : _nv[_j];                    \
                int _ia = _sw ? _nid[_j] : _nid[_i];                    \
                int _ib = _sw ? _nid[_i] : _nid[_j];                    \
                _nv[_i] = _ta; _nv[_j] = _tb;                           \
                _nid[_i] = _ia; _nid[_j] = _ib;                         \
            }                                                           \
        }                                                               \
    }                                                                   \
    _Pragma("unroll")                                                   \
    for (int _i = 0; _i < KNN; ++_i) { VARR[_i] = _nv[_i]; IARR[_i] = _nid[_i]; } \
} while (0)

// Uniform-lane broadcast of a float register (readlane -> SGPR).
__device__ __forceinline__ float rdlane_f(float x, int u) {
    return __uint_as_float((unsigned)__builtin_amdgcn_readlane(
        (int)__float_as_uint(x), u));
}

// Scan the first CNT slots of the register batch (lane u holds point u):
// broadcast via readlane (no memory latency), record passing slots in the
// per-lane 64-bit cand mask; then drain via per-lane bpermute gather +
// chain insert. cand is fully consumed on exit.
#define SCANB(CNT) do {                                                 \
    for (int _u = 0; _u < (CNT); ++_u) {                                \
        float _px = rdlane_f(preg.x, _u);                               \
        float _py = rdlane_f(preg.y, _u);                               \
        float _pz = rdlane_f(preg.z, _u);                               \
        float _dx = _px - qx, _dy = _py - qy, _dz = _pz - qz;           \
        float _dv = fmaf(_dx, _dx, fmaf(_dy, _dy, _dz * _dz));          \
        if (_dv < fcut) cand |= 1ull << _u;                             \
    }                                                                   \
    while (__ballot(cand != 0)) {                                       \
        int _u2 = cand ? (int)(__ffsll((long long)cand) - 1) : 0;       \
        float _gx = __shfl(preg.x, _u2, 64);                            \
        float _gy = __shfl(preg.y, _u2, 64);                            \
        float _gz = __shfl(preg.z, _u2, 64);                            \
        float _gw = __shfl(preg.w, _u2, 64);                            \
        float _dx = _gx - qx, _dy = _gy - qy, _dz = _gz - qz;           \
        float _dv = fmaf(_dx, _dx, fmaf(_dy, _dy, _dz * _dz));          \
        if (cand && _dv < v[KNN - 1])                                   \
            CHAIN_INSERT(_dv, __float_as_int(_gw));                     \
        cand &= cand - 1;                                               \
    }                                                                   \
} while (0)

// ---------------------------------------------------------------------------
// Kernel: FUSED histogram (blocks 0..63) + f = feature1 @ Wp + bp (all 512).
__global__ __launch_bounds__(256) void k_prep(const float* __restrict__ feat,
                                              const float* __restrict__ Wp,
                                              const float* __restrict__ bp,
                                              const float* __restrict__ xyz1,
                                              const float* __restrict__ xyz2,
                                              unsigned* __restrict__ pcount,
                                              unsigned* __restrict__ qcount,
                                              float* __restrict__ f) {
    if (blockIdx.x < 64) {                    // histogram part (16384 threads)
        int i = blockIdx.x * 256 + threadIdx.x;
        int b = i >> 13;
        const float* p = xyz1 + (size_t)i * 3;
        int cx = max(0, min(GC - 1, (int)(p[0] * GC)));
        int cy = max(0, min(GC - 1, (int)(p[1] * GC)));
        int cz = max(0, min(GC - 1, (int)(p[2] * GC)));
        atomicAdd(&pcount[b * NC + (cz * GC + cy) * GC + cx], 1u);
        const float* q = xyz2 + (size_t)i * 3;
        int qx = max(0, min(GC - 1, (int)(q[0] * GC)));
        int qy = max(0, min(GC - 1, (int)(q[1] * GC)));
        int qz = max(0, min(GC - 1, (int)(q[2] * GC)));
        int sc = ((qz >> 2) * 4 + (qy >> 2)) * 4 + (qx >> 2);
        atomicAdd(&qcount[b * NSC + sc], 1u);
    }
    // projection part
    int c  = threadIdx.x & 63;
    int wv = threadIdx.x >> 6;
    int row0 = blockIdx.x * 32 + wv * 8;
    float wp[64];
#pragma unroll
    for (int d = 0; d < 64; ++d) wp[d] = Wp[d * 64 + c];   // coalesced, L1-hot
    float bpc = bp[c];
    float fv[8], acc[8];
#pragma unroll
    for (int r = 0; r < 8; ++r) {
        fv[r]  = feat[(size_t)(row0 + r) * 64 + c];        // coalesced
        acc[r] = bpc;
    }
#pragma unroll
    for (int d = 0; d < 64; ++d) {
#pragma unroll
        for (int r = 0; r < 8; ++r)
            acc[r] = fmaf(__shfl(fv[r], d, 64), wp[d], acc[r]);
    }
#pragma unroll
    for (int r = 0; r < 8; ++r)
        f[(size_t)(row0 + r) * 64 + c] = acc[r];
}

// Kernel: blocks 0,1 = 4096-bin exclusive scan (points, per batch);
//         blocks 2,3 = 64-bin query scan + wave-table build (shfl scans).
// wtab entry packs (qoff<<7) | qnum.
__global__ __launch_bounds__(256) void k_scan(const unsigned* __restrict__ pcount,
                                              const unsigned* __restrict__ qcount,
                                              unsigned* __restrict__ pstart,
                                              unsigned* __restrict__ pcur,
                                              unsigned* __restrict__ qcur,
                                              int* __restrict__ wtab,
                                              int* __restrict__ ntab) {
    __shared__ unsigned wsum[4];
    int blk = blockIdx.x;
    if (blk < 2) {
        int b = blk;
        int t = threadIdx.x;
        int base = b * NC + t * 16;
        unsigned c[16]; unsigned tsum = 0;
#pragma unroll
        for (int k = 0; k < 16; ++k) { c[k] = pcount[base + k]; tsum += c[k]; }
        int lane = t & 63, wv = t >> 6;
        unsigned x = tsum;
#pragma unroll
        for (int off = 1; off < 64; off <<= 1) {
            unsigned y = __shfl_up(x, off, 64);
            if (lane >= off) x += y;
        }
        if (lane == 63) wsum[wv] = x;
        __syncthreads();
        unsigned pre = 0;
        for (int k2 = 0; k2 < wv; ++k2) pre += wsum[k2];
        unsigned run = pre + x - tsum;
#pragma unroll
        for (int k = 0; k < 16; ++k) {
            pstart[base + k] = run; pcur[base + k] = run; run += c[k];
        }
    } else {
        int b = blk - 2;
        if (threadIdx.x >= 64) return;
        int lane = threadIdx.x;
        int c = (int)qcount[b * NSC + lane];
        int x = c;
#pragma unroll
        for (int off = 1; off < 64; off <<= 1) {
            int y = __shfl_up(x, off, 64);
            if (lane >= off) x += y;
        }
        int run = x - c;                         // exclusive prefix of queries
        qcur[b * NSC + lane] = (unsigned)run;
        int ne = (c + 63) >> 6;                  // entries for this supercell
        int e = ne;
#pragma unroll
        for (int off = 1; off < 64; off <<= 1) {
            int y = __shfl_up(e, off, 64);
            if (lane >= off) e += y;
        }
        int eoff = e - ne;                       // exclusive prefix of entries
        for (int j = 0; j < ne; ++j)
            wtab[b * WTMAX + eoff + j] = ((run + j * 64) << 7) | min(64, c - j * 64);
        if (lane == 63) ntab[b] = eoff + ne;
    }
}

// Kernel: scatter points (cell-sorted, |p|^2 in .w) and queries (supercell-sorted).
__global__ __launch_bounds__(256) void k_scatter(const float* __restrict__ xyz1,
                                                 const float* __restrict__ xyz2,
                                                 unsigned* __restrict__ pcur,
                                                 unsigned* __restrict__ qcur,
                                                 float4* __restrict__ spts,
                                                 int* __restrict__ sidx,
                                                 float4* __restrict__ squery) {
    int i = blockIdx.x * 256 + threadIdx.x;   // < B*N
    int b = i >> 13;
    const float* p = xyz1 + (size_t)i * 3;
    float x = p[0], y = p[1], z = p[2];
    int cx = max(0, min(GC - 1, (int)(x * GC)));
    int cy = max(0, min(GC - 1, (int)(y * GC)));
    int cz = max(0, min(GC - 1, (int)(z * GC)));
    unsigned pos = atomicAdd(&pcur[b * NC + (cz * GC + cy) * GC + cx], 1u);
    spts[(size_t)b * N + pos] = make_float4(x, y, z, fmaf(x, x, fmaf(y, y, z * z)));
    sidx[(size_t)b * N + pos] = i & (N - 1);

    const float* q = xyz2 + (size_t)i * 3;
    float qx = q[0], qy = q[1], qz = q[2];
    int ax = max(0, min(GC - 1, (int)(qx * GC)));
    int ay = max(0, min(GC - 1, (int)(qy * GC)));
    int az = max(0, min(GC - 1, (int)(qz * GC)));
    int sc = ((az >> 2) * 4 + (ay >> 2)) * 4 + (ax >> 2);
    unsigned qpos = atomicAdd(&qcur[b * NSC + sc], 1u);
    squery[(size_t)b * M + qpos] = make_float4(qx, qy, qz, __int_as_float(i));
}

// Kernel: grid KNN partials, slice-parallel, templated on slice count NSLT.
// One wave per block, NO LDS. Points live in registers (lane u of the current
// 64-point batch holds point u, assembled by predicated window loads per
// row); scan broadcasts via readlane (VALU pipe -- eliminates the ds_read
// latency that capped R12 at 38% VALUBusy); candidates recorded in a per-lane
// 64-bit mask, drained via bpermute gather + chain insert. Writes the lane's
// SORTED 16-list to the transposed partial layout [sqid][slice][16].
template <int NSLT>
__global__ __launch_bounds__(64) void k_knn(const float4* __restrict__ spts,
                                            const float4* __restrict__ squery,
                                            const unsigned* __restrict__ pstart,
                                            const unsigned* __restrict__ pcount,
                                            const int* __restrict__ wtab,
                                            const int* __restrict__ ntab,
                                            float* __restrict__ part_d,
                                            int* __restrict__ part_i) {
    int bid = blockIdx.x;
    int b   = bid / (WTMAX * NSLT);
    int rem = bid - b * (WTMAX * NSLT);
    int ti  = rem / NSLT;
    int s   = rem % NSLT;                       // slice 0..NSLT-1
    if (ti >= ntab[b]) return;
    int e = wtab[b * WTMAX + ti];
    int qnum = e & 127, qoff = (e >> 7) & 0x3FFF;
    int lane = threadIdx.x;                     // 0..63

    int sl = lane < qnum ? lane : qnum - 1;     // surplus lanes dup last query
    float4 q4 = squery[(size_t)b * M + qoff + sl];
    float qx = q4.x, qy = q4.y, qz = q4.z;
    float cutr = query_cutr(qx, qy, qz);
    float fcut = cutr * cutr;                   // filter in true d^2 space

    int lx0 = max(0, (int)floorf((qx - cutr) * GC));
    int lx1 = min(GC - 1, (int)floorf((qx + cutr) * GC));
    int ly0 = max(0, (int)floorf((qy - cutr) * GC));
    int ly1 = min(GC - 1, (int)floorf((qy + cutr) * GC));
    int lz0 = max(0, (int)floorf((qz - cutr) * GC));
    int lz1 = min(GC - 1, (int)floorf((qz + cutr) * GC));
#pragma unroll
    for (int off = 1; off < 64; off <<= 1) {
        lx0 = min(lx0, __shfl_xor(lx0, off, 64));
        lx1 = max(lx1, __shfl_xor(lx1, off, 64));
        ly0 = min(ly0, __shfl_xor(ly0, off, 64));
        ly1 = max(ly1, __shfl_xor(ly1, off, 64));
        lz0 = min(lz0, __shfl_xor(lz0, off, 64));
        lz1 = max(lz1, __shfl_xor(lz1, off, 64));
    }
    int bx0 = __builtin_amdgcn_readfirstlane(lx0);
    int bx1 = __builtin_amdgcn_readfirstlane(lx1);
    int by0 = __builtin_amdgcn_readfirstlane(ly0);
    int by1 = __builtin_amdgcn_readfirstlane(ly1);
    int bz0 = __builtin_amdgcn_readfirstlane(lz0);
    int bz1 = __builtin_amdgcn_readfirstlane(lz1);

    float v[KNN]; int id[KNN];
#pragma unroll
    for (int r = 0; r < KNN; ++r) { v[r] = 3.4e38f; id[r] = 0; }
    int pb = b * N, cb = b * NC;
    int xspan = bx1 - bx0;

    // Per-lane row table: lane j owns row rix = s + NSLT*j of this box's
    // (z,y) row-major enumeration. All pstart/pcount gathers issue at once.
    int ny = by1 - by0 + 1;
    int nrows = (bz1 - bz0 + 1) * ny;
    int myrows = (s < nrows) ? ((nrows - 1 - s) / NSLT + 1) : 0;  // small
    int stj = 0, enj = 0;
    {
        int rj = s + NSLT * lane;
        if (lane < myrows) {
            int dz = rj / ny;
            int dy = rj - dz * ny;
            int codeL = cb + ((bz0 + dz) * GC + (by0 + dy)) * GC + bx0;
            stj = (int)pstart[codeL];
            enj = (int)pstart[codeL + xspan] + (int)pcount[codeL + xspan];
        }
    }

    unsigned long long cand = 0;
    float4 preg = make_float4(3.4e38f, 3.4e38f, 3.4e38f, 0.f);
    int cur = 0;
    for (int j = 0; j < myrows; ++j) {
        int st = __builtin_amdgcn_readfirstlane(__shfl(stj, j, 64));
        int en = __builtin_amdgcn_readfirstlane(__shfl(enj, j, 64));
        int len = en - st;
        while (len > 0) {
            int take = min(len, 64 - cur);
            if (lane >= cur && lane < cur + take) {
                int addr = st + (lane - cur);            // batch-relative idx
                float4 p = spts[pb + addr];
                p.w = __int_as_float(addr);
                preg = p;
            }
            cur += take; st += take; len -= take;
            if (cur == 64) { SCANB(64); cur = 0; }
        }
    }
    if (cur > 0) SCANB(cur);

    if (lane < qnum) {
        // Transposed layout: [sqid][slice][16], 64B-aligned vector stores.
        size_t base = ((size_t)(b * M + qoff + lane) * NSLT + s) * KNN;
        float4* pd = (float4*)(part_d + base);
        int4*   pi = (int4*)(part_i + base);
#pragma unroll
        for (int r4 = 0; r4 < 4; ++r4) {
            pd[r4] = make_float4(v[r4 * 4 + 0], v[r4 * 4 + 1],
                                 v[r4 * 4 + 2], v[r4 * 4 + 3]);
            pi[r4] = make_int4(id[r4 * 4 + 0], id[r4 * 4 + 1],
                               id[r4 * 4 + 2], id[r4 * 4 + 3]);
        }
    }
}

// Kernel: merge NSLT sorted 16-lists per query. One NSLT-lane group per query
// (64/NSLT queries per wave, no LDS, no syncthreads). Lane gl loads slice
// gl's sorted list (contiguous 64B), log2(NSLT)-round shfl_xor bitonic
// tournament allreduces the global sorted top-16 to all group lanes. Inline
// whole-wave fixup for missed queries. Writes w_out[gq] and
// idx_out[r*BM + sqid] (ORIGINAL indices).
template <int NSLT>
__global__ __launch_bounds__(256, 4) void k_merge(const float4* __restrict__ squery,
                                                  const float* __restrict__ part_d,
                                                  const int* __restrict__ part_i,
                                                  const int* __restrict__ sidx,
                                                  const float4* __restrict__ spts,
                                                  int* __restrict__ idx_out,
                                                  float* __restrict__ w_out) {
    constexpr int GS  = NSLT;           // group size (lanes) = slice count
    constexpr int QPW = 64 / GS;        // queries per wave
    int tid = threadIdx.x;
    int l   = tid & 63;                 // lane in wave
    int wv  = tid >> 6;                 // wave 0..3
    int g   = l / GS;                   // query within wave
    int gl  = l % GS;                   // lane in group = slice idx
    int sqid = blockIdx.x * (QPW * 4) + wv * QPW + g;
    int b = sqid >> 13;

    float v[KNN]; int id[KNN];
    {
        size_t base = ((size_t)sqid * GS + gl) * KNN;
        const float4* pd = (const float4*)(part_d + base);
        const int4*   pi = (const int4*)(part_i + base);
#pragma unroll
        for (int r4 = 0; r4 < 4; ++r4) {
            float4 dv = pd[r4]; int4 iv = pi[r4];
            v[r4 * 4 + 0] = dv.x; v[r4 * 4 + 1] = dv.y;
            v[r4 * 4 + 2] = dv.z; v[r4 * 4 + 3] = dv.w;
            id[r4 * 4 + 0] = iv.x; id[r4 * 4 + 1] = iv.y;
            id[r4 * 4 + 2] = iv.z; id[r4 * 4 + 3] = iv.w;
        }
    }
    // log2(GS)-round tournament; masks stay within the GS-lane group.
#pragma unroll
    for (int dl = 1; dl < GS; dl <<= 1)
        BITONIC_ROUND(v, id, dl);
    // all GS lanes of the group now hold the global sorted top-16

    float4 q4 = squery[sqid];           // group-uniform
    float cutr = query_cutr(q4.x, q4.y, q4.z);
    bool miss = !(v[KNN - 1] < cutr * cutr * 0.9999f);   // group-uniform
    int gq = __float_as_int(q4.w);
    if (!miss) {
        if (gl == 0) w_out[gq] = (v[0] > 0.03f) ? 10.0f : 1.0f;
#pragma unroll
        for (int rr = 0; rr < (KNN + GS - 1) / GS; ++rr) {
            int r = gl + rr * GS;
            if (r < KNN) {
                int myid = 0;
#pragma unroll
                for (int k = 0; k < KNN; ++k) if (r == k) myid = id[k];
                idx_out[(size_t)r * BM + sqid] = sidx[b * N + myid];
            }
        }
    }

    // Whole-wave fixup for missed queries (normally skipped).
    unsigned long long mmask = __ballot(miss && gl == 0);
    while (mmask) {
        int ml = __ffsll(mmask) - 1;
        mmask &= mmask - 1;
        int msq = blockIdx.x * (QPW * 4) + wv * QPW + ml / GS;
        int mb = msq >> 13;
        float4 mq = squery[msq];
        float fv2[KNN]; int fi2[KNN];
#pragma unroll
        for (int r = 0; r < KNN; ++r) { fv2[r] = 3.4e38f; fi2[r] = 0; }
        for (int t = l; t < N; t += 64) {
            float4 p = spts[(size_t)mb * N + t];
            float dx = p.x - mq.x, dy = p.y - mq.y, dz = p.z - mq.z;
            float dv = fmaf(dx, dx, fmaf(dy, dy, dz * dz));
            if (dv < fv2[KNN - 1]) CHAIN_INS(fv2, fi2, dv, t);
        }
        BITONIC_ROUND(fv2, fi2, 1);
        BITONIC_ROUND(fv2, fi2, 2);
        BITONIC_ROUND(fv2, fi2, 4);
        BITONIC_ROUND(fv2, fi2, 8);
        BITONIC_ROUND(fv2, fi2, 16);
        BITONIC_ROUND(fv2, fi2, 32);
        int mgq = __float_as_int(mq.w);
        if (l == 0) w_out[mgq] = (fv2[0] > 0.03f) ? 10.0f : 1.0f;
        if (l < 16) {
            int myid = 0;
#pragma unroll
            for (int r = 0; r < KNN; ++r) if (l == r) myid = fi2[r];
            idx_out[(size_t)l * BM + msq] = sidx[mb * N + myid];
        }
    }
}

// Kernel: MFMA gather+MLP+reduce. ONE query per wave (R5-proven: max TLP for
// the latency-bound gather chains; 2q/wave regressed -14% in R11). mq forced
// wave-uniform (readfirstlane) so the 16 idxs loads compile to scalar loads;
// neighbor ids preloaded once with literal indices (stay in SGPRs).
__global__ __launch_bounds__(256) void k_final(const float4* __restrict__ squery,
                                               const int* __restrict__ idxs,
                                               const float* __restrict__ xyz1,
                                               const float* __restrict__ f,
                                               const float* __restrict__ W1,
                                               const float* __restrict__ b1,
                                               const float* __restrict__ W2,
                                               const float* __restrict__ b2,
                                               float* __restrict__ out) {
    __shared__ __align__(16) unsigned short hT[4][16][72];  // 9 KB, padded bf16
    int tid = threadIdx.x;
    int l   = tid & 63;
    int wv  = tid >> 6;
    int ln  = l & 15, lg = l >> 4;
    int mq  = __builtin_amdgcn_readfirstlane(blockIdx.x * 4 + wv);  // sorted qid
    int bb  = mq >> 13;
    float4 q4 = squery[mq];
    int gq = __float_as_int(q4.w);
    float qx = q4.x, qy = q4.y, qz = q4.z;

    // Preload all 16 neighbor ids (wave-uniform -> scalar loads, issue early).
    int nk[KNN];
#pragma unroll
    for (int k = 0; k < KNN; ++k)
        nk[k] = idxs[(size_t)k * BM + mq];

    // B-frags: B[k=(lg*8+j)+32s][n=ln] = W2[d][t*16+ln]; uniform, L1-hot.
    frag_ab bfrag[4][2];
#pragma unroll
    for (int t = 0; t < 4; ++t)
#pragma unroll
        for (int s = 0; s < 2; ++s) {
            frag_ab bv;
#pragma unroll
            for (int j = 0; j < 8; ++j)
                bv[j] = f2bf(W2[(lg * 8 + j + 32 * s) * 64 + t * 16 + ln]);
            bfrag[t][s] = bv;
        }

    float w10 = W1[l], w11 = W1[64 + l], w12 = W1[128 + l], b1c = b1[l];

    // h in lane=d layout; bf16 transpose into hT[k][d] (d = lane).
#pragma unroll
    for (int k = 0; k < KNN; ++k) {
        const float* p = xyz1 + ((size_t)bb * N + nk[k]) * 3;
        float gx = p[0] - qx, gy = p[1] - qy, gz = p[2] - qz;
        float t = fmaf(gx, w10, b1c);
        t = fmaf(gy, w11, t);
        t = fmaf(gz, w12, t);
        hT[wv][k][l] = (unsigned short)f2bf(fmaxf(t, 0.f));
    }
    // same-wave LDS RAW: compiler inserts lgkmcnt wait.

    frag_cd acc[4];
#pragma unroll
    for (int t = 0; t < 4; ++t) acc[t] = (frag_cd){0.f, 0.f, 0.f, 0.f};
#pragma unroll
    for (int s = 0; s < 2; ++s) {
        frag_ab af = *(const frag_ab*)&hT[wv][ln][lg * 8 + 32 * s];
#pragma unroll
        for (int t = 0; t < 4; ++t)
            acc[t] = __builtin_amdgcn_mfma_f32_16x16x32_bf16(af, bfrag[t][s],
                                                             acc[t], 0, 0, 0);
    }

    // gf rows for this lane's 4 k values (k = lg*4 + i); per-lane reload is
    // L1-hot (same addresses as the scalar preload).
    int nk4[4];
#pragma unroll
    for (int i = 0; i < 4; ++i)
        nk4[i] = idxs[(size_t)(lg * 4 + i) * BM + mq];

#pragma unroll
    for (int t = 0; t < 4; ++t) {
        float b2c = b2[t * 16 + ln];
        float s = 0.f;
#pragma unroll
        for (int i = 0; i < 4; ++i) {
            float gf = f[((size_t)bb * N + nk4[i]) * 64 + t * 16 + ln];
            s = fmaf(acc[t][i] + b2c, gf, s);
        }
        s += __shfl_xor(s, 16, 64);
        s += __shfl_xor(s, 32, 64);
        if (lg == t)
            out[(size_t)gq * 64 + t * 16 + ln] = s * 0.25f;   // 1/sqrt(16)
    }
}

extern "C" void kernel_launch(void* const* d_in, const int* in_sizes, int n_in,
                              void* d_out, int out_size, void* d_ws, size_t ws_size,
                              hipStream_t stream) {
    const float* feature1 = (const float*)d_in[0];
    const float* xyz1     = (const float*)d_in[1];
    const float* xyz2     = (const float*)d_in[2];
    const float* Wp       = (const float*)d_in[3];
    const float* bp       = (const float*)d_in[4];
    const float* W1       = (const float*)d_in[5];
    const float* b1       = (const float*)d_in[6];
    const float* W2       = (const float*)d_in[7];
    const float* b2       = (const float*)d_in[8];
    float* out = (float*)d_out;

    char* w = (char*)d_ws;
    float4*   spts   = (float4*)w;    w += (size_t)B * N * 16;
    float4*   squery = (float4*)w;    w += (size_t)B * M * 16;
    float*    f      = (float*)w;     w += (size_t)B * N * D * 4;
    int*      sidx   = (int*)w;       w += (size_t)B * N * 4;
    unsigned* pcount = (unsigned*)w;  w += (size_t)B * NC * 4;
    unsigned* qcount = (unsigned*)w;  w += (size_t)B * NSC * 4;
    unsigned* pstart = (unsigned*)w;  w += (size_t)B * NC * 4;
    unsigned* pcur   = (unsigned*)w;  w += (size_t)B * NC * 4;
    unsigned* qcur   = (unsigned*)w;  w += (size_t)B * NSC * 4;
    int*      wtab   = (int*)w;       w += (size_t)B * WTMAX * 4;
    int*      ntab   = (int*)w;       w += 16;

    // Slice count by available workspace: NSL=16 proven best (R5).
    size_t used_fixed = (size_t)(w - (char*)d_ws);
    size_t per_slice  = (size_t)KNN * BM * 8;          // partd+parti per slice
    size_t idxf_bytes = (size_t)KNN * BM * 4;
    int nsl = (ws_size >= used_fixed + 16 * per_slice + idxf_bytes) ? 16 : 8;

    float*    partd  = (float*)w;     w += (size_t)nsl * KNN * BM * 4;
    int*      parti  = (int*)w;       w += (size_t)nsl * KNN * BM * 4;
    int*      idxf   = (int*)w;       w += idxf_bytes;
    float*    w_out  = out + (size_t)BM * D;

    // zero pcount + qcount (contiguous)
    hipMemsetAsync(pcount, 0, (size_t)(B * NC + B * NSC) * 4, stream);

    k_prep<<<B * N / 32, 256, 0, stream>>>(feature1, Wp, bp, xyz1, xyz2,
                                           pcount, qcount, f);
    k_scan<<<4, 256, 0, stream>>>(pcount, qcount, pstart, pcur, qcur, wtab, ntab);
    k_scatter<<<BM / 256, 256, 0, stream>>>(xyz1, xyz2, pcur, qcur, spts, sidx, squery);
    if (nsl == 16) {
        k_knn<16><<<B * WTMAX * 16, 64, 0, stream>>>(spts, squery, pstart, pcount,
                                                     wtab, ntab, partd, parti);
        k_merge<16><<<BM / 16, 256, 0, stream>>>(squery, partd, parti, sidx, spts,
                                                 idxf, w_out);
    } else {
        k_knn<8><<<B * WTMAX * 8, 64, 0, stream>>>(spts, squery, pstart, pcount,
                                                   wtab, ntab, partd, parti);
        k_merge<8><<<BM / 32, 256, 0, stream>>>(squery, partd, parti, sidx, spts,
                                                idxf, w_out);
    }
    k_final<<<BM / 4, 256, 0, stream>>>(squery, idxf, xyz1, f,
                                        W1, b1, W2, b2, out);
}

// Round 14
// 178.628 us; speedup vs baseline: 1.1416x; 1.1416x over previous
//
#include <hip/hip_runtime.h>
#include <math.h>

#define B 2
#define N 8192
#define M 8192
#define D 64
#define KNN 16
#define BM (B * M)           // 16384
#define GC 16                // grid cells per axis
#define NC (GC * GC * GC)    // 4096
#define NSC 256              // query bins: 16 (x,y)-columns x 16 z-cells
#define WTMAX 192            // max wave-table entries per batch (<=144 proven)
#define CAP 20               // per-lane LDS candidate buffer slots
#define TCAP 448             // per-wave LDS point-tile capacity

using frag_ab = __attribute__((ext_vector_type(8))) short;   // 8 bf16 (4 VGPRs)
using frag_cd = __attribute__((ext_vector_type(4))) float;   // 4 fp32

// fp32 -> bf16 (round-to-nearest-even), bits in a short.
__device__ __forceinline__ short f2bf(float x) {
    unsigned u = __float_as_uint(x);
    u += 0x7fffu + ((u >> 16) & 1u);
    return (short)(u >> 16);
}

// Per-query filter radius: lambda~60 expected in-(clipped-)ball candidates.
// nc = #axes within 0.16 of a domain wall (density octant compensation).
// MUST be recomputed identically in k_knn and k_merge.
__device__ __forceinline__ float query_cutr(float qx, float qy, float qz) {
    int nc = ((qx < 0.16f) | (qx > 0.84f)) + ((qy < 0.16f) | (qy > 0.84f))
           + ((qz < 0.16f) | (qz > 0.84f));
    return nc == 0 ? 0.121f : nc == 1 ? 0.1525f : nc == 2 ? 0.1921f : 0.242f;
}

// Sorted-insert of (dd,ii) into a per-lane top-16 (ascending). Strict < keeps
// earlier-inserted on exact ties.
#define CHAIN_INS(VARR, IARR, DVAL, IVAL) do {                          \
    float _dd = (DVAL); int _ii = (IVAL);                               \
    _Pragma("unroll")                                                   \
    for (int _r = 0; _r < KNN; ++_r) {                                  \
        bool  _sm = _dd < VARR[_r];                                     \
        float _tv = VARR[_r]; int _ti = IARR[_r];                       \
        VARR[_r] = _sm ? _dd : _tv;  IARR[_r] = _sm ? _ii : _ti;        \
        _dd      = _sm ? _tv : _dd;  _ii      = _sm ? _ti : _ii;        \
    }                                                                   \
} while (0)
#define CHAIN_INSERT(DVAL, IVAL) CHAIN_INS(v, id, DVAL, IVAL)

// One bitonic-merge round between lane and lane^DL: both keep the lowest 16
// of their combined (sorted) lists, result sorted. VARR/IARR must be sorted
// ascending on entry.
#define BITONIC_ROUND(VARR, IARR, DL) do {                              \
    float _nv[KNN]; int _nid[KNN];                                      \
    _Pragma("unroll")                                                   \
    for (int _i = 0; _i < KNN; ++_i) {                                  \
        float _pv = __shfl_xor(VARR[KNN - 1 - _i], (DL), 64);           \
        int   _pi = __shfl_xor(IARR[KNN - 1 - _i], (DL), 64);           \
        bool _tk = VARR[_i] <= _pv;                                     \
        _nv[_i]  = _tk ? VARR[_i] : _pv;                                \
        _nid[_i] = _tk ? IARR[_i] : _pi;                                \
    }                                                                   \
    _Pragma("unroll")                                                   \
    for (int _st = 8; _st; _st >>= 1) {                                 \
        _Pragma("unroll")                                               \
        for (int _i = 0; _i < KNN; ++_i) {                              \
            if (!(_i & _st)) {                                          \
                int _j = _i | _st;                                      \
                bool _sw = _nv[_i] > _nv[_j];                           \
                float _ta = _sw ? _nv[_j] : _nv[_i];                    \
                float _tb = _sw ? _nv[_i] : _nv[_j];                    \
                int _ia = _sw ? _nid[_j] : _nid[_i];                    \
                int _ib = _sw ? _nid[_i] : _nid[_j];                    \
                _nv[_i] = _ta; _nv[_j] = _tb;                           \
                _nid[_i] = _ia; _nid[_j] = _ib;                         \
            }                                                           \
        }                                                               \
    }                                                                   \
    _Pragma("unroll")                                                   \
    for (int _i = 0; _i < KNN; ++_i) { VARR[_i] = _nv[_i]; IARR[_i] = _nid[_i]; } \
} while (0)

// Process one prefetched tile point against this lane's query.
#define KPROC(PV, TV) do {                                              \
    float _dx = (PV).x - qx, _dy = (PV).y - qy, _dz = (PV).z - qz;      \
    float _dv = fmaf(_dx, _dx, fmaf(_dy, _dy, _dz * _dz));              \
    if (_dv < fcut) {                                                   \
        if (cnt < CAP) {                                                \
            ibuf[cnt][lane] = (unsigned short)(TV);                     \
            ++cnt;                                                      \
        } else {                           /* overflow (rare) */        \
            CHAIN_INSERT(_dv, __float_as_int((PV).w));                  \
        }                                                               \
    }                                                                   \
} while (0)

// Scan the wave's tile (4-deep batched broadcast ds_read_b128 so LDS latency
// overlaps), buffer passing tile slots, drain (2-deep, recompute d^2 from
// tile, idx from .w), reset.
#define KFLUSH() do {                                                   \
    int _t = 0;                                                         \
    for (; _t + 4 <= cur; _t += 4) {                                    \
        float4 _q0 = tile[_t + 0], _q1 = tile[_t + 1];                  \
        float4 _q2 = tile[_t + 2], _q3 = tile[_t + 3];                  \
        KPROC(_q0, _t + 0); KPROC(_q1, _t + 1);                         \
        KPROC(_q2, _t + 2); KPROC(_q3, _t + 3);                         \
    }                                                                   \
    for (; _t < cur; ++_t) { float4 _q0 = tile[_t]; KPROC(_q0, _t); }   \
    int _mx = cnt;                                                      \
    _Pragma("unroll")                                                   \
    for (int _o = 32; _o; _o >>= 1)                                     \
        _mx = max(_mx, __shfl_xor(_mx, _o, 64));                        \
    _mx = __builtin_amdgcn_readfirstlane(_mx);                          \
    int _t2 = 0;                                                        \
    for (; _t2 + 2 <= _mx; _t2 += 2) {                                  \
        int _ta = (_t2     < cnt) ? (int)ibuf[_t2    ][lane] : 0;       \
        int _tb = (_t2 + 1 < cnt) ? (int)ibuf[_t2 + 1][lane] : 0;       \
        float4 _pa = tile[_ta], _pb = tile[_tb];   /* batched gathers */\
        float _dxa = _pa.x - qx, _dya = _pa.y - qy, _dza = _pa.z - qz;  \
        float _dva = fmaf(_dxa, _dxa, fmaf(_dya, _dya, _dza * _dza));   \
        if (_t2 < cnt && _dva < v[KNN - 1])                             \
            CHAIN_INSERT(_dva, __float_as_int(_pa.w));                  \
        float _dxb = _pb.x - qx, _dyb = _pb.y - qy, _dzb = _pb.z - qz;  \
        float _dvb = fmaf(_dxb, _dxb, fmaf(_dyb, _dyb, _dzb * _dzb));   \
        if (_t2 + 1 < cnt && _dvb < v[KNN - 1])                         \
            CHAIN_INSERT(_dvb, __float_as_int(_pb.w));                  \
    }                                                                   \
    for (; _t2 < _mx; ++_t2) {                                          \
        int _tp = (_t2 < cnt) ? (int)ibuf[_t2][lane] : 0;               \
        float4 _p = tile[_tp];                                          \
        float _dx = _p.x - qx, _dy = _p.y - qy, _dz = _p.z - qz;        \
        float _dv = fmaf(_dx, _dx, fmaf(_dy, _dy, _dz * _dz));          \
        if (_t2 < cnt && _dv < v[KNN - 1])                              \
            CHAIN_INSERT(_dv, __float_as_int(_p.w));                    \
    }                                                                   \
    cnt = 0; cur = 0;                                                   \
} while (0)

// ---------------------------------------------------------------------------
// Kernel: FUSED histogram (blocks 0..63) + f = feature1 @ Wp + bp (all 512).
__global__ __launch_bounds__(256) void k_prep(const float* __restrict__ feat,
                                              const float* __restrict__ Wp,
                                              const float* __restrict__ bp,
                                              const float* __restrict__ xyz1,
                                              const float* __restrict__ xyz2,
                                              unsigned* __restrict__ pcount,
                                              unsigned* __restrict__ qcount,
                                              float* __restrict__ f) {
    if (blockIdx.x < 64) {                    // histogram part (16384 threads)
        int i = blockIdx.x * 256 + threadIdx.x;
        int b = i >> 13;
        const float* p = xyz1 + (size_t)i * 3;
        int cx = max(0, min(GC - 1, (int)(p[0] * GC)));
        int cy = max(0, min(GC - 1, (int)(p[1] * GC)));
        int cz = max(0, min(GC - 1, (int)(p[2] * GC)));
        atomicAdd(&pcount[b * NC + (cz * GC + cy) * GC + cx], 1u);
        const float* q = xyz2 + (size_t)i * 3;
        int qx = max(0, min(GC - 1, (int)(q[0] * GC)));
        int qy = max(0, min(GC - 1, (int)(q[1] * GC)));
        int qz = max(0, min(GC - 1, (int)(q[2] * GC)));
        int sc = ((qy >> 2) * 4 + (qx >> 2)) * 16 + qz;   // column-major, z-sorted
        atomicAdd(&qcount[b * NSC + sc], 1u);
    }
    // projection part
    int c  = threadIdx.x & 63;
    int wv = threadIdx.x >> 6;
    int row0 = blockIdx.x * 32 + wv * 8;
    float wp[64];
#pragma unroll
    for (int d = 0; d < 64; ++d) wp[d] = Wp[d * 64 + c];   // coalesced, L1-hot
    float bpc = bp[c];
    float fv[8], acc[8];
#pragma unroll
    for (int r = 0; r < 8; ++r) {
        fv[r]  = feat[(size_t)(row0 + r) * 64 + c];        // coalesced
        acc[r] = bpc;
    }
#pragma unroll
    for (int d = 0; d < 64; ++d) {
#pragma unroll
        for (int r = 0; r < 8; ++r)
            acc[r] = fmaf(__shfl(fv[r], d, 64), wp[d], acc[r]);
    }
#pragma unroll
    for (int r = 0; r < 8; ++r)
        f[(size_t)(row0 + r) * 64 + c] = acc[r];
}

// Kernel: blocks 0,1 = 4096-bin exclusive scan (points, per batch);
//         blocks 2,3 = 256-bin query scan + COLUMN-WINDOW wave-table build.
// Queries are binned (column, z-cell); entries are 64-query windows over each
// column's contiguous range -> window z-spread ~0.15-0.19 (vs 0.25), which
// shrinks k_knn's scan box. wtab entry packs (qoff<<7) | qnum.
__global__ __launch_bounds__(256) void k_scan(const unsigned* __restrict__ pcount,
                                              const unsigned* __restrict__ qcount,
                                              unsigned* __restrict__ pstart,
                                              unsigned* __restrict__ pcur,
                                              unsigned* __restrict__ qcur,
                                              int* __restrict__ wtab,
                                              int* __restrict__ ntab) {
    __shared__ unsigned wsum[4];
    int blk = blockIdx.x;
    if (blk < 2) {
        int b = blk;
        int t = threadIdx.x;
        int base = b * NC + t * 16;
        unsigned c[16]; unsigned tsum = 0;
#pragma unroll
        for (int k = 0; k < 16; ++k) { c[k] = pcount[base + k]; tsum += c[k]; }
        int lane = t & 63, wv = t >> 6;
        unsigned x = tsum;
#pragma unroll
        for (int off = 1; off < 64; off <<= 1) {
            unsigned y = __shfl_up(x, off, 64);
            if (lane >= off) x += y;
        }
        if (lane == 63) wsum[wv] = x;
        __syncthreads();
        unsigned pre = 0;
        for (int k2 = 0; k2 < wv; ++k2) pre += wsum[k2];
        unsigned run = pre + x - tsum;
#pragma unroll
        for (int k = 0; k < 16; ++k) {
            pstart[base + k] = run; pcur[base + k] = run; run += c[k];
        }
    } else {
        int b = blk - 2;
        if (threadIdx.x >= 64) return;
        int lane = threadIdx.x;
        // 4 bins per lane (bins 4*lane..4*lane+3; bin = col*16 + zc).
        unsigned c4[4]; unsigned tsum = 0;
#pragma unroll
        for (int k = 0; k < 4; ++k) {
            c4[k] = qcount[b * NSC + 4 * lane + k];
            tsum += c4[k];
        }
        unsigned x = tsum;
#pragma unroll
        for (int off = 1; off < 64; off <<= 1) {
            unsigned y = __shfl_up(x, off, 64);
            if (lane >= off) x += y;
        }
        unsigned run = x - tsum;                 // exclusive prefix @ bin 4*lane
#pragma unroll
        for (int k = 0; k < 4; ++k) {
            qcur[b * NSC + 4 * lane + k] = run; run += c4[k];
        }
        // Column j (j<16) covers lanes 4j..4j+3 (bins 16j..16j+15).
        int xex = (int)(x - tsum);               // excl prefix @ first bin of lane
        int xin = (int)x;                        // incl prefix thru last bin
        int colstart = __shfl(xex, (lane << 2) & 63, 64);
        int colend   = __shfl(xin, ((lane << 2) | 3) & 63, 64);
        int ccol = colend - colstart;            // valid for lane < 16
        int ne = (lane < 16) ? ((ccol + 63) >> 6) : 0;
        int e = ne;
#pragma unroll
        for (int off = 1; off < 64; off <<= 1) {
            int y = __shfl_up(e, off, 64);
            if (lane >= off) e += y;
        }
        int eoff = e - ne;                       // exclusive prefix of entries
        if (lane < 16)
            for (int j = 0; j < ne; ++j)
                wtab[b * WTMAX + eoff + j] =
                    ((colstart + j * 64) << 7) | min(64, ccol - j * 64);
        if (lane == 63) ntab[b] = e;             // total entries
    }
}

// Kernel: scatter points (cell-sorted, |p|^2 in .w) and queries
// (column+z-cell sorted).
__global__ __launch_bounds__(256) void k_scatter(const float* __restrict__ xyz1,
                                                 const float* __restrict__ xyz2,
                                                 unsigned* __restrict__ pcur,
                                                 unsigned* __restrict__ qcur,
                                                 float4* __restrict__ spts,
                                                 int* __restrict__ sidx,
                                                 float4* __restrict__ squery) {
    int i = blockIdx.x * 256 + threadIdx.x;   // < B*N
    int b = i >> 13;
    const float* p = xyz1 + (size_t)i * 3;
    float x = p[0], y = p[1], z = p[2];
    int cx = max(0, min(GC - 1, (int)(x * GC)));
    int cy = max(0, min(GC - 1, (int)(y * GC)));
    int cz = max(0, min(GC - 1, (int)(z * GC)));
    unsigned pos = atomicAdd(&pcur[b * NC + (cz * GC + cy) * GC + cx], 1u);
    spts[(size_t)b * N + pos] = make_float4(x, y, z, fmaf(x, x, fmaf(y, y, z * z)));
    sidx[(size_t)b * N + pos] = i & (N - 1);

    const float* q = xyz2 + (size_t)i * 3;
    float qx = q[0], qy = q[1], qz = q[2];
    int ax = max(0, min(GC - 1, (int)(qx * GC)));
    int ay = max(0, min(GC - 1, (int)(qy * GC)));
    int az = max(0, min(GC - 1, (int)(qz * GC)));
    int sc = ((ay >> 2) * 4 + (ax >> 2)) * 16 + az;       // MUST match k_prep
    unsigned qpos = atomicAdd(&qcur[b * NSC + sc], 1u);
    squery[(size_t)b * M + qpos] = make_float4(qx, qy, qz, __int_as_float(i));
}

// Kernel: grid KNN partials, slice-parallel, templated on slice count NSLT.
// One wave per block (R5/R12-proven structure). Writes the lane's SORTED
// 16-list to the transposed partial layout [sqid][slice][16].
template <int NSLT>
__global__ __launch_bounds__(64) void k_knn(const float4* __restrict__ spts,
                                            const float4* __restrict__ squery,
                                            const unsigned* __restrict__ pstart,
                                            const unsigned* __restrict__ pcount,
                                            const int* __restrict__ wtab,
                                            const int* __restrict__ ntab,
                                            float* __restrict__ part_d,
                                            int* __restrict__ part_i) {
    __shared__ float4         tile[TCAP];      // 7 KB (idx in .w)
    __shared__ unsigned short ibuf[CAP][64];   // 2.5 KB, [slot][lane]
    int bid = blockIdx.x;
    int b   = bid / (WTMAX * NSLT);
    int rem = bid - b * (WTMAX * NSLT);
    int ti  = rem / NSLT;
    int s   = rem % NSLT;                       // slice 0..NSLT-1
    if (ti >= ntab[b]) return;
    int e = wtab[b * WTMAX + ti];
    int qnum = e & 127, qoff = (e >> 7) & 0x3FFF;
    int lane = threadIdx.x;                     // 0..63

    int sl = lane < qnum ? lane : qnum - 1;     // surplus lanes dup last query
    float4 q4 = squery[(size_t)b * M + qoff + sl];
    float qx = q4.x, qy = q4.y, qz = q4.z;
    float cutr = query_cutr(qx, qy, qz);
    float fcut = cutr * cutr;                   // filter in true d^2 space

    int lx0 = max(0, (int)floorf((qx - cutr) * GC));
    int lx1 = min(GC - 1, (int)floorf((qx + cutr) * GC));
    int ly0 = max(0, (int)floorf((qy - cutr) * GC));
    int ly1 = min(GC - 1, (int)floorf((qy + cutr) * GC));
    int lz0 = max(0, (int)floorf((qz - cutr) * GC));
    int lz1 = min(GC - 1, (int)floorf((qz + cutr) * GC));
#pragma unroll
    for (int off = 1; off < 64; off <<= 1) {
        lx0 = min(lx0, __shfl_xor(lx0, off, 64));
        lx1 = max(lx1, __shfl_xor(lx1, off, 64));
        ly0 = min(ly0, __shfl_xor(ly0, off, 64));
        ly1 = max(ly1, __shfl_xor(ly1, off, 64));
        lz0 = min(lz0, __shfl_xor(lz0, off, 64));
        lz1 = max(lz1, __shfl_xor(lz1, off, 64));
    }
    int bx0 = __builtin_amdgcn_readfirstlane(lx0);
    int bx1 = __builtin_amdgcn_readfirstlane(lx1);
    int by0 = __builtin_amdgcn_readfirstlane(ly0);
    int by1 = __builtin_amdgcn_readfirstlane(ly1);
    int bz0 = __builtin_amdgcn_readfirstlane(lz0);
    int bz1 = __builtin_amdgcn_readfirstlane(lz1);

    float v[KNN]; int id[KNN];
#pragma unroll
    for (int r = 0; r < KNN; ++r) { v[r] = 3.4e38f; id[r] = 0; }
    int cnt = 0, cur = 0;
    int pb = b * N, cb = b * NC;
    int xspan = bx1 - bx0;

    // Per-lane row table: lane j owns row rix = s + NSLT*j of this box's
    // (z,y) row-major enumeration. All pstart/pcount gathers issue at once.
    int ny = by1 - by0 + 1;
    int nrows = (bz1 - bz0 + 1) * ny;
    int myrows = (s < nrows) ? ((nrows - 1 - s) / NSLT + 1) : 0;  // small
    int stj = 0, enj = 0;
    {
        int rj = s + NSLT * lane;
        if (lane < myrows) {
            int dz = rj / ny;
            int dy = rj - dz * ny;
            int codeL = cb + ((bz0 + dz) * GC + (by0 + dy)) * GC + bx0;
            stj = (int)pstart[codeL];
            enj = (int)pstart[codeL + xspan] + (int)pcount[codeL + xspan];
        }
    }
    for (int j = 0; j < myrows; ++j) {
        int st = __builtin_amdgcn_readfirstlane(__shfl(stj, j, 64));
        int en = __builtin_amdgcn_readfirstlane(__shfl(enj, j, 64));
        int len = en - st;
        if (cur + len > TCAP) KFLUSH();
        for (int u = lane; u < len; u += 64) {        // vector loads
            float4 p = spts[pb + st + u];
            p.w = __int_as_float(st + u);             // pack sorted idx
            tile[cur + u] = p;
        }
        cur += len;
    }
    KFLUSH();

    if (lane < qnum) {
        // Transposed layout: [sqid][slice][16], 64B-aligned vector stores.
        size_t base = ((size_t)(b * M + qoff + lane) * NSLT + s) * KNN;
        float4* pd = (float4*)(part_d + base);
        int4*   pi = (int4*)(part_i + base);
#pragma unroll
        for (int r4 = 0; r4 < 4; ++r4) {
            pd[r4] = make_float4(v[r4 * 4 + 0], v[r4 * 4 + 1],
                                 v[r4 * 4 + 2], v[r4 * 4 + 3]);
            pi[r4] = make_int4(id[r4 * 4 + 0], id[r4 * 4 + 1],
                               id[r4 * 4 + 2], id[r4 * 4 + 3]);
        }
    }
}

// Kernel: merge NSLT sorted 16-lists per query. One NSLT-lane group per query
// (64/NSLT queries per wave, no LDS, no syncthreads). Lane gl loads slice
// gl's sorted list (contiguous 64B), log2(NSLT)-round shfl_xor bitonic
// tournament allreduces the global sorted top-16 to all group lanes. Inline
// whole-wave fixup for missed queries. Writes w_out[gq] and
// idx_out[r*BM + sqid] (ORIGINAL indices).
template <int NSLT>
__global__ __launch_bounds__(256, 4) void k_merge(const float4* __restrict__ squery,
                                                  const float* __restrict__ part_d,
                                                  const int* __restrict__ part_i,
                                                  const int* __restrict__ sidx,
                                                  const float4* __restrict__ spts,
                                                  int* __restrict__ idx_out,
                                                  float* __restrict__ w_out) {
    constexpr int GS  = NSLT;           // group size (lanes) = slice count
    constexpr int QPW = 64 / GS;        // queries per wave
    int tid = threadIdx.x;
    int l   = tid & 63;                 // lane in wave
    int wv  = tid >> 6;                 // wave 0..3
    int g   = l / GS;                   // query within wave
    int gl  = l % GS;                   // lane in group = slice idx
    int sqid = blockIdx.x * (QPW * 4) + wv * QPW + g;
    int b = sqid >> 13;

    float v[KNN]; int id[KNN];
    {
        size_t base = ((size_t)sqid * GS + gl) * KNN;
        const float4* pd = (const float4*)(part_d + base);
        const int4*   pi = (const int4*)(part_i + base);
#pragma unroll
        for (int r4 = 0; r4 < 4; ++r4) {
            float4 dv = pd[r4]; int4 iv = pi[r4];
            v[r4 * 4 + 0] = dv.x; v[r4 * 4 + 1] = dv.y;
            v[r4 * 4 + 2] = dv.z; v[r4 * 4 + 3] = dv.w;
            id[r4 * 4 + 0] = iv.x; id[r4 * 4 + 1] = iv.y;
            id[r4 * 4 + 2] = iv.z; id[r4 * 4 + 3] = iv.w;
        }
    }
    // log2(GS)-round tournament; masks stay within the GS-lane group.
#pragma unroll
    for (int dl = 1; dl < GS; dl <<= 1)
        BITONIC_ROUND(v, id, dl);
    // all GS lanes of the group now hold the global sorted top-16

    float4 q4 = squery[sqid];           // group-uniform
    float cutr = query_cutr(q4.x, q4.y, q4.z);
    bool miss = !(v[KNN - 1] < cutr * cutr * 0.9999f);   // group-uniform
    int gq = __float_as_int(q4.w);
    if (!miss) {
        if (gl == 0) w_out[gq] = (v[0] > 0.03f) ? 10.0f : 1.0f;
#pragma unroll
        for (int rr = 0; rr < (KNN + GS - 1) / GS; ++rr) {
            int r = gl + rr * GS;
            if (r < KNN) {
                int myid = 0;
#pragma unroll
                for (int k = 0; k < KNN; ++k) if (r == k) myid = id[k];
                idx_out[(size_t)r * BM + sqid] = sidx[b * N + myid];
            }
        }
    }

    // Whole-wave fixup for missed queries (normally skipped).
    unsigned long long mmask = __ballot(miss && gl == 0);
    while (mmask) {
        int ml = __ffsll(mmask) - 1;
        mmask &= mmask - 1;
        int msq = blockIdx.x * (QPW * 4) + wv * QPW + ml / GS;
        int mb = msq >> 13;
        float4 mq = squery[msq];
        float fv2[KNN]; int fi2[KNN];
#pragma unroll
        for (int r = 0; r < KNN; ++r) { fv2[r] = 3.4e38f; fi2[r] = 0; }
        for (int t = l; t < N; t += 64) {
            float4 p = spts[(size_t)mb * N + t];
            float dx = p.x - mq.x, dy = p.y - mq.y, dz = p.z - mq.z;
            float dv = fmaf(dx, dx, fmaf(dy, dy, dz * dz));
            if (dv < fv2[KNN - 1]) CHAIN_INS(fv2, fi2, dv, t);
        }
        BITONIC_ROUND(fv2, fi2, 1);
        BITONIC_ROUND(fv2, fi2, 2);
        BITONIC_ROUND(fv2, fi2, 4);
        BITONIC_ROUND(fv2, fi2, 8);
        BITONIC_ROUND(fv2, fi2, 16);
        BITONIC_ROUND(fv2, fi2, 32);
        int mgq = __float_as_int(mq.w);
        if (l == 0) w_out[mgq] = (fv2[0] > 0.03f) ? 10.0f : 1.0f;
        if (l < 16) {
            int myid = 0;
#pragma unroll
            for (int r = 0; r < KNN; ++r) if (l == r) myid = fi2[r];
            idx_out[(size_t)l * BM + msq] = sidx[mb * N + myid];
        }
    }
}

// Kernel: MFMA gather+MLP+reduce. ONE query per wave (R5-proven: max TLP for
// the latency-bound gather chains). mq wave-uniform (readfirstlane) so the 16
// idxs loads compile to scalar loads; neighbor ids preloaded once.
__global__ __launch_bounds__(256) void k_final(const float4* __restrict__ squery,
                                               const int* __restrict__ idxs,
                                               const float* __restrict__ xyz1,
                                               const float* __restrict__ f,
                                               const float* __restrict__ W1,
                                               const float* __restrict__ b1,
                                               const float* __restrict__ W2,
                                               const float* __restrict__ b2,
                                               float* __restrict__ out) {
    __shared__ __align__(16) unsigned short hT[4][16][72];  // 9 KB, padded bf16
    int tid = threadIdx.x;
    int l   = tid & 63;
    int wv  = tid >> 6;
    int ln  = l & 15, lg = l >> 4;
    int mq  = __builtin_amdgcn_readfirstlane(blockIdx.x * 4 + wv);  // sorted qid
    int bb  = mq >> 13;
    float4 q4 = squery[mq];
    int gq = __float_as_int(q4.w);
    float qx = q4.x, qy = q4.y, qz = q4.z;

    // Preload all 16 neighbor ids (wave-uniform -> scalar loads, issue early).
    int nk[KNN];
#pragma unroll
    for (int k = 0; k < KNN; ++k)
        nk[k] = idxs[(size_t)k * BM + mq];

    // B-frags: B[k=(lg*8+j)+32s][n=ln] = W2[d][t*16+ln]; uniform, L1-hot.
    frag_ab bfrag[4][2];
#pragma unroll
    for (int t = 0; t < 4; ++t)
#pragma unroll
        for (int s = 0; s < 2; ++s) {
            frag_ab bv;
#pragma unroll
            for (int j = 0; j < 8; ++j)
                bv[j] = f2bf(W2[(lg * 8 + j + 32 * s) * 64 + t * 16 + ln]);
            bfrag[t][s] = bv;
        }

    float w10 = W1[l], w11 = W1[64 + l], w12 = W1[128 + l], b1c = b1[l];

    // h in lane=d layout; bf16 transpose into hT[k][d] (d = lane).
#pragma unroll
    for (int k = 0; k < KNN; ++k) {
        const float* p = xyz1 + ((size_t)bb * N + nk[k]) * 3;
        float gx = p[0] - qx, gy = p[1] - qy, gz = p[2] - qz;
        float t = fmaf(gx, w10, b1c);
        t = fmaf(gy, w11, t);
        t = fmaf(gz, w12, t);
        hT[wv][k][l] = (unsigned short)f2bf(fmaxf(t, 0.f));
    }
    // same-wave LDS RAW: compiler inserts lgkmcnt wait.

    frag_cd acc[4];
#pragma unroll
    for (int t = 0; t < 4; ++t) acc[t] = (frag_cd){0.f, 0.f, 0.f, 0.f};
#pragma unroll
    for (int s = 0; s < 2; ++s) {
        frag_ab af = *(const frag_ab*)&hT[wv][ln][lg * 8 + 32 * s];
#pragma unroll
        for (int t = 0; t < 4; ++t)
            acc[t] = __builtin_amdgcn_mfma_f32_16x16x32_bf16(af, bfrag[t][s],
                                                             acc[t], 0, 0, 0);
    }

    // gf rows for this lane's 4 k values (k = lg*4 + i); per-lane reload is
    // L1-hot (same addresses as the scalar preload).
    int nk4[4];
#pragma unroll
    for (int i = 0; i < 4; ++i)
        nk4[i] = idxs[(size_t)(lg * 4 + i) * BM + mq];

#pragma unroll
    for (int t = 0; t < 4; ++t) {
        float b2c = b2[t * 16 + ln];
        float s = 0.f;
#pragma unroll
        for (int i = 0; i < 4; ++i) {
            float gf = f[((size_t)bb * N + nk4[i]) * 64 + t * 16 + ln];
            s = fmaf(acc[t][i] + b2c, gf, s);
        }
        s += __shfl_xor(s, 16, 64);
        s += __shfl_xor(s, 32, 64);
        if (lg == t)
            out[(size_t)gq * 64 + t * 16 + ln] = s * 0.25f;   // 1/sqrt(16)
    }
}

extern "C" void kernel_launch(void* const* d_in, const int* in_sizes, int n_in,
                              void* d_out, int out_size, void* d_ws, size_t ws_size,
                              hipStream_t stream) {
    const float* feature1 = (const float*)d_in[0];
    const float* xyz1     = (const float*)d_in[1];
    const float* xyz2     = (const float*)d_in[2];
    const float* Wp       = (const float*)d_in[3];
    const float* bp       = (const float*)d_in[4];
    const float* W1       = (const float*)d_in[5];
    const float* b1       = (const float*)d_in[6];
    const float* W2       = (const float*)d_in[7];
    const float* b2       = (const float*)d_in[8];
    float* out = (float*)d_out;

    char* w = (char*)d_ws;
    float4*   spts   = (float4*)w;    w += (size_t)B * N * 16;
    float4*   squery = (float4*)w;    w += (size_t)B * M * 16;
    float*    f      = (float*)w;     w += (size_t)B * N * D * 4;
    int*      sidx   = (int*)w;       w += (size_t)B * N * 4;
    unsigned* pcount = (unsigned*)w;  w += (size_t)B * NC * 4;
    unsigned* qcount = (unsigned*)w;  w += (size_t)B * NSC * 4;
    unsigned* pstart = (unsigned*)w;  w += (size_t)B * NC * 4;
    unsigned* pcur   = (unsigned*)w;  w += (size_t)B * NC * 4;
    unsigned* qcur   = (unsigned*)w;  w += (size_t)B * NSC * 4;
    int*      wtab   = (int*)w;       w += (size_t)B * WTMAX * 4;
    int*      ntab   = (int*)w;       w += 16;

    // Slice count by available workspace: NSL=16 proven best (R5/R12).
    size_t used_fixed = (size_t)(w - (char*)d_ws);
    size_t per_slice  = (size_t)KNN * BM * 8;          // partd+parti per slice
    size_t idxf_bytes = (size_t)KNN * BM * 4;
    int nsl = (ws_size >= used_fixed + 16 * per_slice + idxf_bytes) ? 16 : 8;

    float*    partd  = (float*)w;     w += (size_t)nsl * KNN * BM * 4;
    int*      parti  = (int*)w;       w += (size_t)nsl * KNN * BM * 4;
    int*      idxf   = (int*)w;       w += idxf_bytes;
    float*    w_out  = out + (size_t)BM * D;

    // zero pcount + qcount (contiguous)
    hipMemsetAsync(pcount, 0, (size_t)(B * NC + B * NSC) * 4, stream);

    k_prep<<<B * N / 32, 256, 0, stream>>>(feature1, Wp, bp, xyz1, xyz2,
                                           pcount, qcount, f);
    k_scan<<<4, 256, 0, stream>>>(pcount, qcount, pstart, pcur, qcur, wtab, ntab);
    k_scatter<<<BM / 256, 256, 0, stream>>>(xyz1, xyz2, pcur, qcur, spts, sidx, squery);
    if (nsl == 16) {
        k_knn<16><<<B * WTMAX * 16, 64, 0, stream>>>(spts, squery, pstart, pcount,
                                                     wtab, ntab, partd, parti);
        k_merge<16><<<BM / 16, 256, 0, stream>>>(squery, partd, parti, sidx, spts,
                                                 idxf, w_out);
    } else {
        k_knn<8><<<B * WTMAX * 8, 64, 0, stream>>>(spts, squery, pstart, pcount,
                                                   wtab, ntab, partd, parti);
        k_merge<8><<<BM / 32, 256, 0, stream>>>(squery, partd, parti, sidx, spts,
                                                idxf, w_out);
    }
    k_final<<<BM / 4, 256, 0, stream>>>(squery, idxf, xyz1, f,
                                        W1, b1, W2, b2, out);
}

// Round 15
// 175.938 us; speedup vs baseline: 1.1591x; 1.0153x over previous
//
#include <hip/hip_runtime.h>
#include <math.h>

#define B 2
#define N 8192
#define M 8192
#define D 64
#define KNN 16
#define BM (B * M)           // 16384
#define GC 16                // grid cells per axis
#define NC (GC * GC * GC)    // 4096
#define NSC 256              // query bins: 16 (x,y)-columns x 16 z-cells
#define WTMAX 192            // max wave-table entries per batch (<=144 proven)
#define CAP 20               // per-lane LDS candidate buffer slots
#define TCAP 448             // per-wave LDS point-tile capacity

using frag_ab = __attribute__((ext_vector_type(8))) short;   // 8 bf16 (4 VGPRs)
using frag_cd = __attribute__((ext_vector_type(4))) float;   // 4 fp32

// fp32 -> bf16 (round-to-nearest-even), bits in a short.
__device__ __forceinline__ short f2bf(float x) {
    unsigned u = __float_as_uint(x);
    u += 0x7fffu + ((u >> 16) & 1u);
    return (short)(u >> 16);
}

// Per-query filter radius: lambda~40 expected in-(clipped-)ball candidates
// (R15: scaled 0.87x from lambda~60 -- P(16th NN outside) ~ 5e-5, and any
// miss is corrected by k_merge's brute-force fixup; box volume -20%).
// nc = #axes within 0.14 of a domain wall (density octant compensation).
// MUST be recomputed identically in k_knn and k_merge.
__device__ __forceinline__ float query_cutr(float qx, float qy, float qz) {
    int nc = ((qx < 0.14f) | (qx > 0.86f)) + ((qy < 0.14f) | (qy > 0.86f))
           + ((qz < 0.14f) | (qz > 0.86f));
    return nc == 0 ? 0.105f : nc == 1 ? 0.133f : nc == 2 ? 0.167f : 0.211f;
}

// Sorted-insert of (dd,ii) into a per-lane top-16 (ascending). Strict < keeps
// earlier-inserted on exact ties.
#define CHAIN_INS(VARR, IARR, DVAL, IVAL) do {                          \
    float _dd = (DVAL); int _ii = (IVAL);                               \
    _Pragma("unroll")                                                   \
    for (int _r = 0; _r < KNN; ++_r) {                                  \
        bool  _sm = _dd < VARR[_r];                                     \
        float _tv = VARR[_r]; int _ti = IARR[_r];                       \
        VARR[_r] = _sm ? _dd : _tv;  IARR[_r] = _sm ? _ii : _ti;        \
        _dd      = _sm ? _tv : _dd;  _ii      = _sm ? _ti : _ii;        \
    }                                                                   \
} while (0)
#define CHAIN_INSERT(DVAL, IVAL) CHAIN_INS(v, id, DVAL, IVAL)

// One bitonic-merge round between lane and lane^DL: both keep the lowest 16
// of their combined (sorted) lists, result sorted. VARR/IARR must be sorted
// ascending on entry.
#define BITONIC_ROUND(VARR, IARR, DL) do {                              \
    float _nv[KNN]; int _nid[KNN];                                      \
    _Pragma("unroll")                                                   \
    for (int _i = 0; _i < KNN; ++_i) {                                  \
        float _pv = __shfl_xor(VARR[KNN - 1 - _i], (DL), 64);           \
        int   _pi = __shfl_xor(IARR[KNN - 1 - _i], (DL), 64);           \
        bool _tk = VARR[_i] <= _pv;                                     \
        _nv[_i]  = _tk ? VARR[_i] : _pv;                                \
        _nid[_i] = _tk ? IARR[_i] : _pi;                                \
    }                                                                   \
    _Pragma("unroll")                                                   \
    for (int _st = 8; _st; _st >>= 1) {                                 \
        _Pragma("unroll")                                               \
        for (int _i = 0; _i < KNN; ++_i) {                              \
            if (!(_i & _st)) {                                          \
                int _j = _i | _st;                                      \
                bool _sw = _nv[_i] > _nv[_j];                           \
                float _ta = _sw ? _nv[_j] : _nv[_i];                    \
                float _tb = _sw ? _nv[_i] : _nv[_j];                    \
                int _ia = _sw ? _nid[_j] : _nid[_i];                    \
                int _ib = _sw ? _nid[_i] : _nid[_j];                    \
                _nv[_i] = _ta; _nv[_j] = _tb;                           \
                _nid[_i] = _ia; _nid[_j] = _ib;                         \
            }                                                           \
        }                                                               \
    }                                                                   \
    _Pragma("unroll")                                                   \
    for (int _i = 0; _i < KNN; ++_i) { VARR[_i] = _nv[_i]; IARR[_i] = _nid[_i]; } \
} while (0)

// Process one prefetched tile point against this lane's query.
#define KPROC(PV, TV) do {                                              \
    float _dx = (PV).x - qx, _dy = (PV).y - qy, _dz = (PV).z - qz;      \
    float _dv = fmaf(_dx, _dx, fmaf(_dy, _dy, _dz * _dz));              \
    if (_dv < fcut) {                                                   \
        if (cnt < CAP) {                                                \
            ibuf[cnt][lane] = (unsigned short)(TV);                     \
            ++cnt;                                                      \
        } else {                           /* overflow (rare) */        \
            CHAIN_INSERT(_dv, __float_as_int((PV).w));                  \
        }                                                               \
    }                                                                   \
} while (0)

// Scan the wave's tile (4-deep batched broadcast ds_read_b128 so LDS latency
// overlaps), buffer passing tile slots, drain (2-deep, recompute d^2 from
// tile, idx from .w), reset.
#define KFLUSH() do {                                                   \
    int _t = 0;                                                         \
    for (; _t + 4 <= cur; _t += 4) {                                    \
        float4 _q0 = tile[_t + 0], _q1 = tile[_t + 1];                  \
        float4 _q2 = tile[_t + 2], _q3 = tile[_t + 3];                  \
        KPROC(_q0, _t + 0); KPROC(_q1, _t + 1);                         \
        KPROC(_q2, _t + 2); KPROC(_q3, _t + 3);                         \
    }                                                                   \
    for (; _t < cur; ++_t) { float4 _q0 = tile[_t]; KPROC(_q0, _t); }   \
    int _mx = cnt;                                                      \
    _Pragma("unroll")                                                   \
    for (int _o = 32; _o; _o >>= 1)                                     \
        _mx = max(_mx, __shfl_xor(_mx, _o, 64));                        \
    _mx = __builtin_amdgcn_readfirstlane(_mx);                          \
    int _t2 = 0;                                                        \
    for (; _t2 + 2 <= _mx; _t2 += 2) {                                  \
        int _ta = (_t2     < cnt) ? (int)ibuf[_t2    ][lane] : 0;       \
        int _tb = (_t2 + 1 < cnt) ? (int)ibuf[_t2 + 1][lane] : 0;       \
        float4 _pa = tile[_ta], _pb = tile[_tb];   /* batched gathers */\
        float _dxa = _pa.x - qx, _dya = _pa.y - qy, _dza = _pa.z - qz;  \
        float _dva = fmaf(_dxa, _dxa, fmaf(_dya, _dya, _dza * _dza));   \
        if (_t2 < cnt && _dva < v[KNN - 1])                             \
            CHAIN_INSERT(_dva, __float_as_int(_pa.w));                  \
        float _dxb = _pb.x - qx, _dyb = _pb.y - qy, _dzb = _pb.z - qz;  \
        float _dvb = fmaf(_dxb, _dxb, fmaf(_dyb, _dyb, _dzb * _dzb));   \
        if (_t2 + 1 < cnt && _dvb < v[KNN - 1])                         \
            CHAIN_INSERT(_dvb, __float_as_int(_pb.w));                  \
    }                                                                   \
    for (; _t2 < _mx; ++_t2) {                                          \
        int _tp = (_t2 < cnt) ? (int)ibuf[_t2][lane] : 0;               \
        float4 _p = tile[_tp];                                          \
        float _dx = _p.x - qx, _dy = _p.y - qy, _dz = _p.z - qz;        \
        float _dv = fmaf(_dx, _dx, fmaf(_dy, _dy, _dz * _dz));          \
        if (_t2 < cnt && _dv < v[KNN - 1])                              \
            CHAIN_INSERT(_dv, __float_as_int(_p.w));                    \
    }                                                                   \
    cnt = 0; cur = 0;                                                   \
} while (0)

// ---------------------------------------------------------------------------
// Kernel: FUSED histogram (blocks 0..63) + f = feature1 @ Wp + bp (all 512).
__global__ __launch_bounds__(256) void k_prep(const float* __restrict__ feat,
                                              const float* __restrict__ Wp,
                                              const float* __restrict__ bp,
                                              const float* __restrict__ xyz1,
                                              const float* __restrict__ xyz2,
                                              unsigned* __restrict__ pcount,
                                              unsigned* __restrict__ qcount,
                                              float* __restrict__ f) {
    if (blockIdx.x < 64) {                    // histogram part (16384 threads)
        int i = blockIdx.x * 256 + threadIdx.x;
        int b = i >> 13;
        const float* p = xyz1 + (size_t)i * 3;
        int cx = max(0, min(GC - 1, (int)(p[0] * GC)));
        int cy = max(0, min(GC - 1, (int)(p[1] * GC)));
        int cz = max(0, min(GC - 1, (int)(p[2] * GC)));
        atomicAdd(&pcount[b * NC + (cz * GC + cy) * GC + cx], 1u);
        const float* q = xyz2 + (size_t)i * 3;
        int qx = max(0, min(GC - 1, (int)(q[0] * GC)));
        int qy = max(0, min(GC - 1, (int)(q[1] * GC)));
        int qz = max(0, min(GC - 1, (int)(q[2] * GC)));
        int sc = ((qy >> 2) * 4 + (qx >> 2)) * 16 + qz;   // column-major, z-sorted
        atomicAdd(&qcount[b * NSC + sc], 1u);
    }
    // projection part
    int c  = threadIdx.x & 63;
    int wv = threadIdx.x >> 6;
    int row0 = blockIdx.x * 32 + wv * 8;
    float wp[64];
#pragma unroll
    for (int d = 0; d < 64; ++d) wp[d] = Wp[d * 64 + c];   // coalesced, L1-hot
    float bpc = bp[c];
    float fv[8], acc[8];
#pragma unroll
    for (int r = 0; r < 8; ++r) {
        fv[r]  = feat[(size_t)(row0 + r) * 64 + c];        // coalesced
        acc[r] = bpc;
    }
#pragma unroll
    for (int d = 0; d < 64; ++d) {
#pragma unroll
        for (int r = 0; r < 8; ++r)
            acc[r] = fmaf(__shfl(fv[r], d, 64), wp[d], acc[r]);
    }
#pragma unroll
    for (int r = 0; r < 8; ++r)
        f[(size_t)(row0 + r) * 64 + c] = acc[r];
}

// Kernel: blocks 0,1 = 4096-bin exclusive scan (points, per batch);
//         blocks 2,3 = 256-bin query scan + COLUMN-WINDOW wave-table build.
// Queries are binned (column, z-cell); entries are 64-query windows over each
// column's contiguous range -> window z-spread ~0.15-0.19 (vs 0.25), which
// shrinks k_knn's scan box. wtab entry packs (qoff<<7) | qnum.
__global__ __launch_bounds__(256) void k_scan(const unsigned* __restrict__ pcount,
                                              const unsigned* __restrict__ qcount,
                                              unsigned* __restrict__ pstart,
                                              unsigned* __restrict__ pcur,
                                              unsigned* __restrict__ qcur,
                                              int* __restrict__ wtab,
                                              int* __restrict__ ntab) {
    __shared__ unsigned wsum[4];
    int blk = blockIdx.x;
    if (blk < 2) {
        int b = blk;
        int t = threadIdx.x;
        int base = b * NC + t * 16;
        unsigned c[16]; unsigned tsum = 0;
#pragma unroll
        for (int k = 0; k < 16; ++k) { c[k] = pcount[base + k]; tsum += c[k]; }
        int lane = t & 63, wv = t >> 6;
        unsigned x = tsum;
#pragma unroll
        for (int off = 1; off < 64; off <<= 1) {
            unsigned y = __shfl_up(x, off, 64);
            if (lane >= off) x += y;
        }
        if (lane == 63) wsum[wv] = x;
        __syncthreads();
        unsigned pre = 0;
        for (int k2 = 0; k2 < wv; ++k2) pre += wsum[k2];
        unsigned run = pre + x - tsum;
#pragma unroll
        for (int k = 0; k < 16; ++k) {
            pstart[base + k] = run; pcur[base + k] = run; run += c[k];
        }
    } else {
        int b = blk - 2;
        if (threadIdx.x >= 64) return;
        int lane = threadIdx.x;
        // 4 bins per lane (bins 4*lane..4*lane+3; bin = col*16 + zc).
        unsigned c4[4]; unsigned tsum = 0;
#pragma unroll
        for (int k = 0; k < 4; ++k) {
            c4[k] = qcount[b * NSC + 4 * lane + k];
            tsum += c4[k];
        }
        unsigned x = tsum;
#pragma unroll
        for (int off = 1; off < 64; off <<= 1) {
            unsigned y = __shfl_up(x, off, 64);
            if (lane >= off) x += y;
        }
        unsigned run = x - tsum;                 // exclusive prefix @ bin 4*lane
#pragma unroll
        for (int k = 0; k < 4; ++k) {
            qcur[b * NSC + 4 * lane + k] = run; run += c4[k];
        }
        // Column j (j<16) covers lanes 4j..4j+3 (bins 16j..16j+15).
        int xex = (int)(x - tsum);               // excl prefix @ first bin of lane
        int xin = (int)x;                        // incl prefix thru last bin
        int colstart = __shfl(xex, (lane << 2) & 63, 64);
        int colend   = __shfl(xin, ((lane << 2) | 3) & 63, 64);
        int ccol = colend - colstart;            // valid for lane < 16
        int ne = (lane < 16) ? ((ccol + 63) >> 6) : 0;
        int e = ne;
#pragma unroll
        for (int off = 1; off < 64; off <<= 1) {
            int y = __shfl_up(e, off, 64);
            if (lane >= off) e += y;
        }
        int eoff = e - ne;                       // exclusive prefix of entries
        if (lane < 16)
            for (int j = 0; j < ne; ++j)
                wtab[b * WTMAX + eoff + j] =
                    ((colstart + j * 64) << 7) | min(64, ccol - j * 64);
        if (lane == 63) ntab[b] = e;             // total entries
    }
}

// Kernel: scatter points (cell-sorted, |p|^2 in .w) and queries
// (column+z-cell sorted).
__global__ __launch_bounds__(256) void k_scatter(const float* __restrict__ xyz1,
                                                 const float* __restrict__ xyz2,
                                                 unsigned* __restrict__ pcur,
                                                 unsigned* __restrict__ qcur,
                                                 float4* __restrict__ spts,
                                                 int* __restrict__ sidx,
                                                 float4* __restrict__ squery) {
    int i = blockIdx.x * 256 + threadIdx.x;   // < B*N
    int b = i >> 13;
    const float* p = xyz1 + (size_t)i * 3;
    float x = p[0], y = p[1], z = p[2];
    int cx = max(0, min(GC - 1, (int)(x * GC)));
    int cy = max(0, min(GC - 1, (int)(y * GC)));
    int cz = max(0, min(GC - 1, (int)(z * GC)));
    unsigned pos = atomicAdd(&pcur[b * NC + (cz * GC + cy) * GC + cx], 1u);
    spts[(size_t)b * N + pos] = make_float4(x, y, z, fmaf(x, x, fmaf(y, y, z * z)));
    sidx[(size_t)b * N + pos] = i & (N - 1);

    const float* q = xyz2 + (size_t)i * 3;
    float qx = q[0], qy = q[1], qz = q[2];
    int ax = max(0, min(GC - 1, (int)(qx * GC)));
    int ay = max(0, min(GC - 1, (int)(qy * GC)));
    int az = max(0, min(GC - 1, (int)(qz * GC)));
    int sc = ((ay >> 2) * 4 + (ax >> 2)) * 16 + az;       // MUST match k_prep
    unsigned qpos = atomicAdd(&qcur[b * NSC + sc], 1u);
    squery[(size_t)b * M + qpos] = make_float4(qx, qy, qz, __int_as_float(i));
}

// Kernel: grid KNN partials, slice-parallel, templated on slice count NSLT.
// One wave per block (R5/R12-proven structure). Writes the lane's SORTED
// 16-list to the transposed partial layout [sqid][slice][16].
template <int NSLT>
__global__ __launch_bounds__(64) void k_knn(const float4* __restrict__ spts,
                                            const float4* __restrict__ squery,
                                            const unsigned* __restrict__ pstart,
                                            const unsigned* __restrict__ pcount,
                                            const int* __restrict__ wtab,
                                            const int* __restrict__ ntab,
                                            float* __restrict__ part_d,
                                            int* __restrict__ part_i) {
    __shared__ float4         tile[TCAP];      // 7 KB (idx in .w)
    __shared__ unsigned short ibuf[CAP][64];   // 2.5 KB, [slot][lane]
    int bid = blockIdx.x;
    int b   = bid / (WTMAX * NSLT);
    int rem = bid - b * (WTMAX * NSLT);
    int ti  = rem / NSLT;
    int s   = rem % NSLT;                       // slice 0..NSLT-1
    if (ti >= ntab[b]) return;
    int e = wtab[b * WTMAX + ti];
    int qnum = e & 127, qoff = (e >> 7) & 0x3FFF;
    int lane = threadIdx.x;                     // 0..63

    int sl = lane < qnum ? lane : qnum - 1;     // surplus lanes dup last query
    float4 q4 = squery[(size_t)b * M + qoff + sl];
    float qx = q4.x, qy = q4.y, qz = q4.z;
    float cutr = query_cutr(qx, qy, qz);
    float fcut = cutr * cutr;                   // filter in true d^2 space

    int lx0 = max(0, (int)floorf((qx - cutr) * GC));
    int lx1 = min(GC - 1, (int)floorf((qx + cutr) * GC));
    int ly0 = max(0, (int)floorf((qy - cutr) * GC));
    int ly1 = min(GC - 1, (int)floorf((qy + cutr) * GC));
    int lz0 = max(0, (int)floorf((qz - cutr) * GC));
    int lz1 = min(GC - 1, (int)floorf((qz + cutr) * GC));
#pragma unroll
    for (int off = 1; off < 64; off <<= 1) {
        lx0 = min(lx0, __shfl_xor(lx0, off, 64));
        lx1 = max(lx1, __shfl_xor(lx1, off, 64));
        ly0 = min(ly0, __shfl_xor(ly0, off, 64));
        ly1 = max(ly1, __shfl_xor(ly1, off, 64));
        lz0 = min(lz0, __shfl_xor(lz0, off, 64));
        lz1 = max(lz1, __shfl_xor(lz1, off, 64));
    }
    int bx0 = __builtin_amdgcn_readfirstlane(lx0);
    int bx1 = __builtin_amdgcn_readfirstlane(lx1);
    int by0 = __builtin_amdgcn_readfirstlane(ly0);
    int by1 = __builtin_amdgcn_readfirstlane(ly1);
    int bz0 = __builtin_amdgcn_readfirstlane(lz0);
    int bz1 = __builtin_amdgcn_readfirstlane(lz1);

    float v[KNN]; int id[KNN];
#pragma unroll
    for (int r = 0; r < KNN; ++r) { v[r] = 3.4e38f; id[r] = 0; }
    int cnt = 0, cur = 0;
    int pb = b * N, cb = b * NC;
    int xspan = bx1 - bx0;

    // Per-lane row table: lane j owns row rix = s + NSLT*j of this box's
    // (z,y) row-major enumeration. All pstart/pcount gathers issue at once.
    int ny = by1 - by0 + 1;
    int nrows = (bz1 - bz0 + 1) * ny;
    int myrows = (s < nrows) ? ((nrows - 1 - s) / NSLT + 1) : 0;  // small
    int stj = 0, enj = 0;
    {
        int rj = s + NSLT * lane;
        if (lane < myrows) {
            int dz = rj / ny;
            int dy = rj - dz * ny;
            int codeL = cb + ((bz0 + dz) * GC + (by0 + dy)) * GC + bx0;
            stj = (int)pstart[codeL];
            enj = (int)pstart[codeL + xspan] + (int)pcount[codeL + xspan];
        }
    }
    for (int j = 0; j < myrows; ++j) {
        int st = __builtin_amdgcn_readfirstlane(__shfl(stj, j, 64));
        int en = __builtin_amdgcn_readfirstlane(__shfl(enj, j, 64));
        int len = en - st;
        if (cur + len > TCAP) KFLUSH();
        for (int u = lane; u < len; u += 64) {        // vector loads
            float4 p = spts[pb + st + u];
            p.w = __int_as_float(st + u);             // pack sorted idx
            tile[cur + u] = p;
        }
        cur += len;
    }
    KFLUSH();

    if (lane < qnum) {
        // Transposed layout: [sqid][slice][16], 64B-aligned vector stores.
        size_t base = ((size_t)(b * M + qoff + lane) * NSLT + s) * KNN;
        float4* pd = (float4*)(part_d + base);
        int4*   pi = (int4*)(part_i + base);
#pragma unroll
        for (int r4 = 0; r4 < 4; ++r4) {
            pd[r4] = make_float4(v[r4 * 4 + 0], v[r4 * 4 + 1],
                                 v[r4 * 4 + 2], v[r4 * 4 + 3]);
            pi[r4] = make_int4(id[r4 * 4 + 0], id[r4 * 4 + 1],
                               id[r4 * 4 + 2], id[r4 * 4 + 3]);
        }
    }
}

// Kernel: merge NSLT sorted 16-lists per query. One NSLT-lane group per query
// (64/NSLT queries per wave, no LDS, no syncthreads). Lane gl loads slice
// gl's sorted list (contiguous 64B), log2(NSLT)-round shfl_xor bitonic
// tournament allreduces the global sorted top-16 to all group lanes. Inline
// whole-wave fixup for missed queries. Writes w_out[gq] and
// idx_out[r*BM + sqid] (ORIGINAL indices).
template <int NSLT>
__global__ __launch_bounds__(256, 4) void k_merge(const float4* __restrict__ squery,
                                                  const float* __restrict__ part_d,
                                                  const int* __restrict__ part_i,
                                                  const int* __restrict__ sidx,
                                                  const float4* __restrict__ spts,
                                                  int* __restrict__ idx_out,
                                                  float* __restrict__ w_out) {
    constexpr int GS  = NSLT;           // group size (lanes) = slice count
    constexpr int QPW = 64 / GS;        // queries per wave
    int tid = threadIdx.x;
    int l   = tid & 63;                 // lane in wave
    int wv  = tid >> 6;                 // wave 0..3
    int g   = l / GS;                   // query within wave
    int gl  = l % GS;                   // lane in group = slice idx
    int sqid = blockIdx.x * (QPW * 4) + wv * QPW + g;
    int b = sqid >> 13;

    float v[KNN]; int id[KNN];
    {
        size_t base = ((size_t)sqid * GS + gl) * KNN;
        const float4* pd = (const float4*)(part_d + base);
        const int4*   pi = (const int4*)(part_i + base);
#pragma unroll
        for (int r4 = 0; r4 < 4; ++r4) {
            float4 dv = pd[r4]; int4 iv = pi[r4];
            v[r4 * 4 + 0] = dv.x; v[r4 * 4 + 1] = dv.y;
            v[r4 * 4 + 2] = dv.z; v[r4 * 4 + 3] = dv.w;
            id[r4 * 4 + 0] = iv.x; id[r4 * 4 + 1] = iv.y;
            id[r4 * 4 + 2] = iv.z; id[r4 * 4 + 3] = iv.w;
        }
    }
    // log2(GS)-round tournament; masks stay within the GS-lane group.
#pragma unroll
    for (int dl = 1; dl < GS; dl <<= 1)
        BITONIC_ROUND(v, id, dl);
    // all GS lanes of the group now hold the global sorted top-16

    float4 q4 = squery[sqid];           // group-uniform
    float cutr = query_cutr(q4.x, q4.y, q4.z);
    bool miss = !(v[KNN - 1] < cutr * cutr * 0.9999f);   // group-uniform
    int gq = __float_as_int(q4.w);
    if (!miss) {
        if (gl == 0) w_out[gq] = (v[0] > 0.03f) ? 10.0f : 1.0f;
#pragma unroll
        for (int rr = 0; rr < (KNN + GS - 1) / GS; ++rr) {
            int r = gl + rr * GS;
            if (r < KNN) {
                int myid = 0;
#pragma unroll
                for (int k = 0; k < KNN; ++k) if (r == k) myid = id[k];
                idx_out[(size_t)r * BM + sqid] = sidx[b * N + myid];
            }
        }
    }

    // Whole-wave fixup for missed queries (normally skipped).
    unsigned long long mmask = __ballot(miss && gl == 0);
    while (mmask) {
        int ml = __ffsll(mmask) - 1;
        mmask &= mmask - 1;
        int msq = blockIdx.x * (QPW * 4) + wv * QPW + ml / GS;
        int mb = msq >> 13;
        float4 mq = squery[msq];
        float fv2[KNN]; int fi2[KNN];
#pragma unroll
        for (int r = 0; r < KNN; ++r) { fv2[r] = 3.4e38f; fi2[r] = 0; }
        for (int t = l; t < N; t += 64) {
            float4 p = spts[(size_t)mb * N + t];
            float dx = p.x - mq.x, dy = p.y - mq.y, dz = p.z - mq.z;
            float dv = fmaf(dx, dx, fmaf(dy, dy, dz * dz));
            if (dv < fv2[KNN - 1]) CHAIN_INS(fv2, fi2, dv, t);
        }
        BITONIC_ROUND(fv2, fi2, 1);
        BITONIC_ROUND(fv2, fi2, 2);
        BITONIC_ROUND(fv2, fi2, 4);
        BITONIC_ROUND(fv2, fi2, 8);
        BITONIC_ROUND(fv2, fi2, 16);
        BITONIC_ROUND(fv2, fi2, 32);
        int mgq = __float_as_int(mq.w);
        if (l == 0) w_out[mgq] = (fv2[0] > 0.03f) ? 10.0f : 1.0f;
        if (l < 16) {
            int myid = 0;
#pragma unroll
            for (int r = 0; r < KNN; ++r) if (l == r) myid = fi2[r];
            idx_out[(size_t)l * BM + msq] = sidx[mb * N + myid];
        }
    }
}

// Kernel: MFMA gather+MLP+reduce. ONE query per wave (R5-proven: max TLP for
// the latency-bound gather chains). mq wave-uniform (readfirstlane) so the 16
// idxs loads compile to scalar loads; neighbor ids preloaded once.
__global__ __launch_bounds__(256) void k_final(const float4* __restrict__ squery,
                                               const int* __restrict__ idxs,
                                               const float* __restrict__ xyz1,
                                               const float* __restrict__ f,
                                               const float* __restrict__ W1,
                                               const float* __restrict__ b1,
                                               const float* __restrict__ W2,
                                               const float* __restrict__ b2,
                                               float* __restrict__ out) {
    __shared__ __align__(16) unsigned short hT[4][16][72];  // 9 KB, padded bf16
    int tid = threadIdx.x;
    int l   = tid & 63;
    int wv  = tid >> 6;
    int ln  = l & 15, lg = l >> 4;
    int mq  = __builtin_amdgcn_readfirstlane(blockIdx.x * 4 + wv);  // sorted qid
    int bb  = mq >> 13;
    float4 q4 = squery[mq];
    int gq = __float_as_int(q4.w);
    float qx = q4.x, qy = q4.y, qz = q4.z;

    // Preload all 16 neighbor ids (wave-uniform -> scalar loads, issue early).
    int nk[KNN];
#pragma unroll
    for (int k = 0; k < KNN; ++k)
        nk[k] = idxs[(size_t)k * BM + mq];

    // B-frags: B[k=(lg*8+j)+32s][n=ln] = W2[d][t*16+ln]; uniform, L1-hot.
    frag_ab bfrag[4][2];
#pragma unroll
    for (int t = 0; t < 4; ++t)
#pragma unroll
        for (int s = 0; s < 2; ++s) {
            frag_ab bv;
#pragma unroll
            for (int j = 0; j < 8; ++j)
                bv[j] = f2bf(W2[(lg * 8 + j + 32 * s) * 64 + t * 16 + ln]);
            bfrag[t][s] = bv;
        }

    float w10 = W1[l], w11 = W1[64 + l], w12 = W1[128 + l], b1c = b1[l];

    // h in lane=d layout; bf16 transpose into hT[k][d] (d = lane).
#pragma unroll
    for (int k = 0; k < KNN; ++k) {
        const float* p = xyz1 + ((size_t)bb * N + nk[k]) * 3;
        float gx = p[0] - qx, gy = p[1] - qy, gz = p[2] - qz;
        float t = fmaf(gx, w10, b1c);
        t = fmaf(gy, w11, t);
        t = fmaf(gz, w12, t);
        hT[wv][k][l] = (unsigned short)f2bf(fmaxf(t, 0.f));
    }
    // same-wave LDS RAW: compiler inserts lgkmcnt wait.

    frag_cd acc[4];
#pragma unroll
    for (int t = 0; t < 4; ++t) acc[t] = (frag_cd){0.f, 0.f, 0.f, 0.f};
#pragma unroll
    for (int s = 0; s < 2; ++s) {
        frag_ab af = *(const frag_ab*)&hT[wv][ln][lg * 8 + 32 * s];
#pragma unroll
        for (int t = 0; t < 4; ++t)
            acc[t] = __builtin_amdgcn_mfma_f32_16x16x32_bf16(af, bfrag[t][s],
                                                             acc[t], 0, 0, 0);
    }

    // gf rows for this lane's 4 k values (k = lg*4 + i); per-lane reload is
    // L1-hot (same addresses as the scalar preload).
    int nk4[4];
#pragma unroll
    for (int i = 0; i < 4; ++i)
        nk4[i] = idxs[(size_t)(lg * 4 + i) * BM + mq];

#pragma unroll
    for (int t = 0; t < 4; ++t) {
        float b2c = b2[t * 16 + ln];
        float s = 0.f;
#pragma unroll
        for (int i = 0; i < 4; ++i) {
            float gf = f[((size_t)bb * N + nk4[i]) * 64 + t * 16 + ln];
            s = fmaf(acc[t][i] + b2c, gf, s);
        }
        s += __shfl_xor(s, 16, 64);
        s += __shfl_xor(s, 32, 64);
        if (lg == t)
            out[(size_t)gq * 64 + t * 16 + ln] = s * 0.25f;   // 1/sqrt(16)
    }
}

extern "C" void kernel_launch(void* const* d_in, const int* in_sizes, int n_in,
                              void* d_out, int out_size, void* d_ws, size_t ws_size,
                              hipStream_t stream) {
    const float* feature1 = (const float*)d_in[0];
    const float* xyz1     = (const float*)d_in[1];
    const float* xyz2     = (const float*)d_in[2];
    const float* Wp       = (const float*)d_in[3];
    const float* bp       = (const float*)d_in[4];
    const float* W1       = (const float*)d_in[5];
    const float* b1       = (const float*)d_in[6];
    const float* W2       = (const float*)d_in[7];
    const float* b2       = (const float*)d_in[8];
    float* out = (float*)d_out;

    char* w = (char*)d_ws;
    float4*   spts   = (float4*)w;    w += (size_t)B * N * 16;
    float4*   squery = (float4*)w;    w += (size_t)B * M * 16;
    float*    f      = (float*)w;     w += (size_t)B * N * D * 4;
    int*      sidx   = (int*)w;       w += (size_t)B * N * 4;
    unsigned* pcount = (unsigned*)w;  w += (size_t)B * NC * 4;
    unsigned* qcount = (unsigned*)w;  w += (size_t)B * NSC * 4;
    unsigned* pstart = (unsigned*)w;  w += (size_t)B * NC * 4;
    unsigned* pcur   = (unsigned*)w;  w += (size_t)B * NC * 4;
    unsigned* qcur   = (unsigned*)w;  w += (size_t)B * NSC * 4;
    int*      wtab   = (int*)w;       w += (size_t)B * WTMAX * 4;
    int*      ntab   = (int*)w;       w += 16;

    // Slice count by available workspace: NSL=16 proven best (R5/R12).
    size_t used_fixed = (size_t)(w - (char*)d_ws);
    size_t per_slice  = (size_t)KNN * BM * 8;          // partd+parti per slice
    size_t idxf_bytes = (size_t)KNN * BM * 4;
    int nsl = (ws_size >= used_fixed + 16 * per_slice + idxf_bytes) ? 16 : 8;

    float*    partd  = (float*)w;     w += (size_t)nsl * KNN * BM * 4;
    int*      parti  = (int*)w;       w += (size_t)nsl * KNN * BM * 4;
    int*      idxf   = (int*)w;       w += idxf_bytes;
    float*    w_out  = out + (size_t)BM * D;

    // zero pcount + qcount (contiguous)
    hipMemsetAsync(pcount, 0, (size_t)(B * NC + B * NSC) * 4, stream);

    k_prep<<<B * N / 32, 256, 0, stream>>>(feature1, Wp, bp, xyz1, xyz2,
                                           pcount, qcount, f);
    k_scan<<<4, 256, 0, stream>>>(pcount, qcount, pstart, pcur, qcur, wtab, ntab);
    k_scatter<<<BM / 256, 256, 0, stream>>>(xyz1, xyz2, pcur, qcur, spts, sidx, squery);
    if (nsl == 16) {
        k_knn<16><<<B * WTMAX * 16, 64, 0, stream>>>(spts, squery, pstart, pcount,
                                                     wtab, ntab, partd, parti);
        k_merge<16><<<BM / 16, 256, 0, stream>>>(squery, partd, parti, sidx, spts,
                                                 idxf, w_out);
    } else {
        k_knn<8><<<B * WTMAX * 8, 64, 0, stream>>>(spts, squery, pstart, pcount,
                                                   wtab, ntab, partd, parti);
        k_merge<8><<<BM / 32, 256, 0, stream>>>(squery, partd, parti, sidx, spts,
                                                idxf, w_out);
    }
    k_final<<<BM / 4, 256, 0, stream>>>(squery, idxf, xyz1, f,
                                        W1, b1, W2, b2, out);
}